// Round 15
// baseline (318.977 us; speedup 1.0000x reference)
//
#include <hip/hip_runtime.h>

typedef __bf16 bf16x4 __attribute__((ext_vector_type(4)));
typedef short  s16x4  __attribute__((ext_vector_type(4)));
typedef float  f32x4  __attribute__((ext_vector_type(4)));

#define DEVFN static __device__ __forceinline__
#define BLOCK 512
#define NWAVES 8
#define RT 4            // 4 row-tiles = 64 rows per wave-group (ILP lever)

// D = A*B + C, 16x16x16 bf16. A = weight frag (A[n][k], k=4g+i), B = data frag
// (B[k=4g+i][m=lane&15]), D[n=4g+r][m=lane&15].
// Chain property: D's (g,r) mapping == next layer's B (g,i) mapping.
//
// log2e-folding: activations carry a log2e scale (W1+b1, b2..b7 scaled by
// log2e, W8 by ln2); silu in scaled space needs no per-value log2e mul.
DEVFN f32x4 mfma16(bf16x4 a, bf16x4 b, f32x4 c) {
  s16x4 as = __builtin_bit_cast(s16x4, a);
  s16x4 bs = __builtin_bit_cast(s16x4, b);
  return __builtin_amdgcn_mfma_f32_16x16x16bf16_1k(as, bs, c, 0, 0, 0);
}

// simple silu (round-12 form): independent exp->rcp chains, best ILP.
// (batched-reciprocal REGRESSED in r13: trans ops pipeline fine, the serial
// product tree added dependency stalls.)
DEVFN float silu_scaled(float y) {            // y = log2e*z ; returns log2e*silu(z)
  float e = __builtin_amdgcn_exp2f(-y);       // free neg modifier
  return y * __builtin_amdgcn_rcpf(1.0f + e);
}

DEVFN bf16x4 pksilu(f32x4 t) {
  bf16x4 r;
#pragma unroll
  for (int j = 0; j < 4; ++j) r[j] = (__bf16)silu_scaled(t[j]);
  return r;
}

// sched fence: blocks DS reordering across this point. Stops the scheduler
// hoisting weight ds_reads across phases (round-9 spill storm: 1.1 GB FETCH).
DEVFN void sbar() { __builtin_amdgcn_sched_barrier(0x7F); }

// ---------------- LDS layout (bytes): 48 KiB, shared by 8 waves ----------------
// frag = 64 lanes x 8B (4 bf16) = 512B; elem(lane,i) = W[16ks+4*(lane>>4)+i][16nt+(lane&15)]
#define OFF_W1   0u        // 8 frags (nt=0..7; k=0..5 real, k=6 = b1 row, rest 0)
#define OFF_W2   4096u     // 8ks x 3nt = 24 frags
#define OFF_W3   16384u    // 3ks x 3nt = 9 frags
#define OFF_W4   20992u
#define OFF_W5   25600u
#define OFF_W6   30208u
#define OFF_W7   34816u    // 3ks x 8nt = 24 frags
#define OFF_BIAS 47104u    // 512 floats (b2..b6 b7 b8pad)
#define SMEM_TOTAL 49152u  // 48 KiB; grid=512 -> 2 blocks/CU

#define LOG2E 1.44269504f
#define LN2   0.69314718f

DEVFN void packW(unsigned char* smem, unsigned base, const float* W, int K, int N, int tid) {
  int NT = N >> 4;
  int total = (K >> 4) * NT * 256;          // 256 elems per frag
  for (int t = tid; t < total; t += BLOCK) {
    int i = t & 3, ln = (t >> 2) & 63, f = t >> 8;
    int ks = f / NT, nt = f - ks * NT;
    int k = 16 * ks + 4 * (ln >> 4) + i;
    int n = 16 * nt + (ln & 15);
    *(__bf16*)(smem + base + (unsigned)f * 512u + (unsigned)ln * 8u + (unsigned)i * 2u)
        = (__bf16)W[k * N + n];
  }
}

DEVFN f32x4 ldb(const float* sB, int off, int nt, int g) {   // bias C-init frag
  return *(const f32x4*)(sB + off + nt * 16 + 4 * g);
}

DEVFN bf16x4 ldw(const unsigned char* smem, unsigned addr) { // weight A-frag (2-way bank: free)
  return *(const bf16x4*)(smem + addr);
}

// generic 48->48 layer over RT row-tiles, weights from LDS
DEVFN void layer33(const unsigned char* smem, unsigned wbase, const float* sB, int bOffL,
                   unsigned wOff, int g, const bf16x4 (&xin)[RT][3], bf16x4 (&xout)[RT][3]) {
  f32x4 acc[RT][3];
#pragma unroll
  for (int nt = 0; nt < 3; ++nt) {
    f32x4 bi = ldb(sB, bOffL, nt, g);
#pragma unroll
    for (int rt = 0; rt < RT; ++rt) acc[rt][nt] = bi;
  }
#pragma unroll
  for (int ks = 0; ks < 3; ++ks)
#pragma unroll
    for (int nt = 0; nt < 3; ++nt) {
      bf16x4 w = ldw(smem, wbase + (unsigned)(ks * 3 + nt) * 512u + wOff);
#pragma unroll
      for (int rt = 0; rt < RT; ++rt)
        acc[rt][nt] = mfma16(w, xin[rt][ks], acc[rt][nt]);
    }
#pragma unroll
  for (int nt = 0; nt < 3; ++nt)
#pragma unroll
    for (int rt = 0; rt < RT; ++rt)
      xout[rt][nt] = pksilu(acc[rt][nt]);
}

// input rows: k=0..5 = (d0,d1,d2,x0,x1,x2), k=6 = constant 1 (b1 row);
// lane(g,m) holds k=4g..4g+3 of row m, converted straight to bf16x4.
DEVFN void loadIn6b(const float* __restrict__ dims, const float* __restrict__ xyz,
                    int grp, int g, int m, int N, bf16x4 (&buf)[RT]) {
#pragma unroll
  for (int rt = 0; rt < RT; ++rt) {
    float v0 = 0.f, v1 = 0.f, v2 = 0.f, v3 = 0.f;
    int row = grp * (RT * 16) + rt * 16 + m;
    if (g == 0) {
      if (row < N) {
        const float* dp = dims + (size_t)row * 3u;
        v0 = dp[0]; v1 = dp[1]; v2 = dp[2];
        v3 = xyz[(size_t)row * 3u];
      }
    } else if (g == 1) {
      if (row < N) {
        const float* xp = xyz + (size_t)row * 3u;
        v0 = xp[1]; v1 = xp[2];
      }
      v2 = 1.f;   // k=6: constant-1 column -> b1 rides W1's k=6 row
    }
    buf[rt][0] = (__bf16)v0; buf[rt][1] = (__bf16)v1;
    buf[rt][2] = (__bf16)v2; buf[rt][3] = (__bf16)v3;
  }
}

__global__ void __launch_bounds__(BLOCK, 3)
pinn_mlp_kernel(const float* __restrict__ dims, const float* __restrict__ xyz,
                const float* __restrict__ W1, const float* __restrict__ b1,
                const float* __restrict__ W2, const float* __restrict__ b2,
                const float* __restrict__ W3, const float* __restrict__ b3,
                const float* __restrict__ W4, const float* __restrict__ b4,
                const float* __restrict__ W5, const float* __restrict__ b5,
                const float* __restrict__ W6, const float* __restrict__ b6,
                const float* __restrict__ W7, const float* __restrict__ b7,
                const float* __restrict__ W8, const float* __restrict__ b8,
                float* __restrict__ out, int N) {
  __shared__ __align__(16) unsigned char smem[SMEM_TOTAL];
  const int tid  = threadIdx.x;
  const int lane = tid & 63;
  const int wave = tid >> 6;
  const int m    = lane & 15;
  const int g    = lane >> 4;

  // ---------------- weight / bias packing (once per block, 8 waves share) ----------------
  for (int t = tid; t < 2048; t += BLOCK) {       // W1*log2e, k=6 row = b1*log2e
    int i = t & 3, ln = (t >> 2) & 63, nt = t >> 8;
    int k = 4 * (ln >> 4) + i;
    int n = 16 * nt + (ln & 15);
    float v = (k < 6) ? W1[k * 128 + n] * LOG2E : (k == 6 ? b1[n] * LOG2E : 0.f);
    *(__bf16*)(smem + OFF_W1 + (unsigned)nt * 512u + (unsigned)ln * 8u + (unsigned)i * 2u) = (__bf16)v;
  }
  packW(smem, OFF_W2, W2, 128, 48, tid);
  packW(smem, OFF_W3, W3, 48, 48, tid);
  packW(smem, OFF_W4, W4, 48, 48, tid);
  packW(smem, OFF_W5, W5, 48, 48, tid);
  packW(smem, OFF_W6, W6, 48, 48, tid);
  packW(smem, OFF_W7, W7, 48, 128, tid);
  float* sBw = (float*)(smem + OFF_BIAS);
  for (int t = tid; t < 512; t += BLOCK) {        // b2..b7 * log2e ; b8 raw ; pad 0
    float v;
    if      (t < 128) v = 0.f;
    else if (t < 176) v = b2[t - 128] * LOG2E;
    else if (t < 224) v = b3[t - 176] * LOG2E;
    else if (t < 272) v = b4[t - 224] * LOG2E;
    else if (t < 320) v = b5[t - 272] * LOG2E;
    else if (t < 368) v = b6[t - 320] * LOG2E;
    else if (t < 496) v = b7[t - 368] * LOG2E;
    else if (t < 499) v = b8[t - 496];
    else              v = 0.f;
    sBw[t] = v;
  }

  // W8 * ln2 in registers: A[n=m][k=16ks+4g+i], n<3 real (16 VGPRs)
  bf16x4 w8f[8];
#pragma unroll
  for (int ks = 0; ks < 8; ++ks) {
    w8f[ks][0] = (__bf16)0.f; w8f[ks][1] = (__bf16)0.f;
    w8f[ks][2] = (__bf16)0.f; w8f[ks][3] = (__bf16)0.f;
    if (m < 3) {
#pragma unroll
      for (int i = 0; i < 4; ++i) {
        int k = 16 * ks + 4 * g + i;
        w8f[ks][i] = (__bf16)(W8[k * 3 + m] * LN2);
      }
    }
  }

  __syncthreads();   // the ONLY workgroup barrier

  const float* sB = (const float*)(smem + OFF_BIAS);
  const unsigned wOff = (unsigned)lane * 8u;

  const int nGroups  = (N + RT * 16 - 1) / (RT * 16);
  const int gw0      = blockIdx.x * NWAVES + wave;
  const int gwStride = gridDim.x * NWAVES;

  bf16x4 inC[RT], inN[RT];
  loadIn6b(dims, xyz, gw0, g, m, N, inC);

  for (int grp = gw0; grp < nGroups; grp += gwStride) {
    const int base = grp * (RT * 16);

    loadIn6b(dims, xyz, grp + gwStride, g, m, N, inN);   // prefetch next group
    sbar();

    const f32x4 z4 = {0.f, 0.f, 0.f, 0.f};

    // ---- L1 -> L2 fused, 2 ntiles at a time ----
    f32x4 acc2[RT][3];
#pragma unroll
    for (int nt = 0; nt < 3; ++nt) {
      f32x4 bi = ldb(sB, 128, nt, g);                   // b2~
#pragma unroll
      for (int rt = 0; rt < RT; ++rt) acc2[rt][nt] = bi;
    }
#pragma unroll
    for (int p = 0; p < 4; ++p) {
      bf16x4 y[RT][2];
#pragma unroll
      for (int c = 0; c < 2; ++c) {                     // produce L1 out ntile 2p+c
        int nt = 2 * p + c;
        bf16x4 w = ldw(smem, OFF_W1 + (unsigned)nt * 512u + wOff);
#pragma unroll
        for (int rt = 0; rt < RT; ++rt)
          y[rt][c] = pksilu(mfma16(w, inC[rt], z4));    // b1 rides W1 k=6
      }
      sbar();
#pragma unroll
      for (int c = 0; c < 2; ++c) {                     // consume as L2 k-step 2p+c
        int ks = 2 * p + c;
#pragma unroll
        for (int nt = 0; nt < 3; ++nt) {
          bf16x4 w = ldw(smem, OFF_W2 + (unsigned)(ks * 3 + nt) * 512u + wOff);
#pragma unroll
          for (int rt = 0; rt < RT; ++rt)
            acc2[rt][nt] = mfma16(w, y[rt][c], acc2[rt][nt]);
        }
      }
      sbar();
    }
    bf16x4 xa[RT][3], xb[RT][3];
#pragma unroll
    for (int nt = 0; nt < 3; ++nt)
#pragma unroll
      for (int rt = 0; rt < RT; ++rt)
        xa[rt][nt] = pksilu(acc2[rt][nt]);
    sbar();

    // ---- 48-wide chain ----
    layer33(smem, OFF_W3, sB, 176, wOff, g, xa, xb); sbar();
    layer33(smem, OFF_W4, sB, 224, wOff, g, xb, xa); sbar();
    layer33(smem, OFF_W5, sB, 272, wOff, g, xa, xb); sbar();
    layer33(smem, OFF_W6, sB, 320, wOff, g, xb, xa); sbar();
    // xa = x6~ (input to L7)

    // ---- L7 -> L8 fused, 2 ntiles at a time ----
    f32x4 acc8[RT];
    {
      f32x4 bi8 = ldb(sB, 496, 0, g);                   // b8 padded (zeros for g>0)
#pragma unroll
      for (int rt = 0; rt < RT; ++rt) acc8[rt] = bi8;
    }
#pragma unroll
    for (int p = 0; p < 4; ++p) {
      f32x4 a7[RT][2];
#pragma unroll
      for (int c = 0; c < 2; ++c) {
        f32x4 bi = ldb(sB, 368, 2 * p + c, g);          // b7~
#pragma unroll
        for (int rt = 0; rt < RT; ++rt) a7[rt][c] = bi;
      }
#pragma unroll
      for (int ks = 0; ks < 3; ++ks)
#pragma unroll
        for (int c = 0; c < 2; ++c) {
          bf16x4 w = ldw(smem, OFF_W7 + (unsigned)(ks * 8 + 2 * p + c) * 512u + wOff);
#pragma unroll
          for (int rt = 0; rt < RT; ++rt)
            a7[rt][c] = mfma16(w, xa[rt][ks], a7[rt][c]);
        }
      sbar();
#pragma unroll
      for (int c = 0; c < 2; ++c)
#pragma unroll
        for (int rt = 0; rt < RT; ++rt) {
          bf16x4 x7 = pksilu(a7[rt][c]);
          acc8[rt] = mfma16(w8f[2 * p + c], x7, acc8[rt]);
        }
      sbar();
    }

    // ---- store fp32 output: lane (g==0, m) owns row base+16rt+m, 3 consecutive floats ----
    if (g == 0) {
#pragma unroll
      for (int rt = 0; rt < RT; ++rt) {
        int row = base + rt * 16 + m;
        if (row < N) {
          size_t o = (size_t)row * 3u;
          out[o + 0] = acc8[rt][0];
          out[o + 1] = acc8[rt][1];
          out[o + 2] = acc8[rt][2];
        }
      }
    }

    // rotate prefetched inputs
#pragma unroll
    for (int rt = 0; rt < RT; ++rt) inC[rt] = inN[rt];
  }
}

extern "C" void kernel_launch(void* const* d_in, const int* in_sizes, int n_in,
                              void* d_out, int out_size, void* d_ws, size_t ws_size,
                              hipStream_t stream) {
  const float* dims = (const float*)d_in[0];
  const float* xyz  = (const float*)d_in[1];
  const float* W1 = (const float*)d_in[2];  const float* b1 = (const float*)d_in[3];
  const float* W2 = (const float*)d_in[4];  const float* b2 = (const float*)d_in[5];
  const float* W3 = (const float*)d_in[6];  const float* b3 = (const float*)d_in[7];
  const float* W4 = (const float*)d_in[8];  const float* b4 = (const float*)d_in[9];
  const float* W5 = (const float*)d_in[10]; const float* b5 = (const float*)d_in[11];
  const float* W6 = (const float*)d_in[12]; const float* b6 = (const float*)d_in[13];
  const float* W7 = (const float*)d_in[14]; const float* b7 = (const float*)d_in[15];
  const float* W8 = (const float*)d_in[16]; const float* b8 = (const float*)d_in[17];
  float* out = (float*)d_out;
  const int N = in_sizes[0] / 3;

  pinn_mlp_kernel<<<dim3(512), dim3(BLOCK), 0, stream>>>(
      dims, xyz, W1, b1, W2, b2, W3, b3, W4, b4, W5, b5, W6, b6, W7, b7, W8, b8,
      out, N);
}

// Round 16
// 275.596 us; speedup vs baseline: 1.1574x; 1.1574x over previous
//
#include <hip/hip_runtime.h>

typedef __bf16 bf16x4 __attribute__((ext_vector_type(4)));
typedef short  s16x4  __attribute__((ext_vector_type(4)));
typedef float  f32x4  __attribute__((ext_vector_type(4)));

#define DEVFN static __device__ __forceinline__
#define BLOCK 512
#define NWAVES 8

// D = A*B + C, 16x16x16 bf16. A = weight frag (A[n][k], k=4g+i), B = data frag
// (B[k=4g+i][m=lane&15]), D[n=4g+r][m=lane&15].
// Chain property: D's (g,r) mapping == next layer's B (g,i) mapping.
//
// log2e-folding: activations carry a log2e scale (W1+b1, b2..b7 scaled by
// log2e, W8 by ln2); silu in scaled space needs no per-value log2e mul.
// b1 rides W1's spare k=6 row against a constant-1 input column.
DEVFN f32x4 mfma16(bf16x4 a, bf16x4 b, f32x4 c) {
  s16x4 as = __builtin_bit_cast(s16x4, a);
  s16x4 bs = __builtin_bit_cast(s16x4, b);
  return __builtin_amdgcn_mfma_f32_16x16x16bf16_1k(as, bs, c, 0, 0, 0);
}

// simple silu: independent exp->rcp chains, best ILP (r13 batched-rcp regressed).
DEVFN float silu_scaled(float y) {            // y = log2e*z ; returns log2e*silu(z)
  float e = __builtin_amdgcn_exp2f(-y);       // free neg modifier
  return y * __builtin_amdgcn_rcpf(1.0f + e);
}

DEVFN bf16x4 pksilu(f32x4 t) {
  bf16x4 r;
#pragma unroll
  for (int j = 0; j < 4; ++j) r[j] = (__bf16)silu_scaled(t[j]);
  return r;
}

// sched fence: blocks DS reordering across this point. Stops the scheduler
// hoisting weight ds_reads across phases (round-9 spill storm: 1.1 GB FETCH).
DEVFN void sbar() { __builtin_amdgcn_sched_barrier(0x7F); }

// ---------------- LDS layout (bytes): 48 KiB, shared by 8 waves ----------------
// frag = 64 lanes x 8B (4 bf16) = 512B; elem(lane,i) = W[16ks+4*(lane>>4)+i][16nt+(lane&15)]
#define OFF_W1   0u        // 8 frags (nt=0..7; k=0..5 real, k=6 = b1 row, rest 0)
#define OFF_W2   4096u     // 8ks x 3nt = 24 frags
#define OFF_W3   16384u    // 3ks x 3nt = 9 frags
#define OFF_W4   20992u
#define OFF_W5   25600u
#define OFF_W6   30208u
#define OFF_W7   34816u    // 3ks x 8nt = 24 frags
#define OFF_BIAS 47104u    // 512 floats (b2..b6 b7 b8pad)
#define SMEM_TOTAL 49152u  // 48 KiB; grid=512 -> 2 blocks/CU

#define LOG2E 1.44269504f
#define LN2   0.69314718f

DEVFN void packW(unsigned char* smem, unsigned base, const float* W, int K, int N, int tid) {
  int NT = N >> 4;
  int total = (K >> 4) * NT * 256;          // 256 elems per frag
  for (int t = tid; t < total; t += BLOCK) {
    int i = t & 3, ln = (t >> 2) & 63, f = t >> 8;
    int ks = f / NT, nt = f - ks * NT;
    int k = 16 * ks + 4 * (ln >> 4) + i;
    int n = 16 * nt + (ln & 15);
    *(__bf16*)(smem + base + (unsigned)f * 512u + (unsigned)ln * 8u + (unsigned)i * 2u)
        = (__bf16)W[k * N + n];
  }
}

DEVFN f32x4 ldb(const float* sB, int off, int nt, int g) {   // bias C-init frag
  return *(const f32x4*)(sB + off + nt * 16 + 4 * g);
}

DEVFN bf16x4 ldw(const unsigned char* smem, unsigned addr) { // weight A-frag (2-way bank: free)
  return *(const bf16x4*)(smem + addr);
}

// generic 48->48 layer, fully register-resident
DEVFN void layer33(const unsigned char* smem, unsigned wbase, const float* sB, int bOffL,
                   unsigned wOff, int g, const bf16x4 (&xin)[2][3], bf16x4 (&xout)[2][3]) {
  f32x4 acc[2][3];
#pragma unroll
  for (int nt = 0; nt < 3; ++nt) {
    f32x4 bi = ldb(sB, bOffL, nt, g);
    acc[0][nt] = bi; acc[1][nt] = bi;
  }
#pragma unroll
  for (int ks = 0; ks < 3; ++ks)
#pragma unroll
    for (int nt = 0; nt < 3; ++nt) {
      bf16x4 w = ldw(smem, wbase + (unsigned)(ks * 3 + nt) * 512u + wOff);
      acc[0][nt] = mfma16(w, xin[0][ks], acc[0][nt]);
      acc[1][nt] = mfma16(w, xin[1][ks], acc[1][nt]);
    }
#pragma unroll
  for (int nt = 0; nt < 3; ++nt) {
    xout[0][nt] = pksilu(acc[0][nt]);
    xout[1][nt] = pksilu(acc[1][nt]);
  }
}

// input rows: k=0..5 = (d0,d1,d2,x0,x1,x2), k=6 = constant 1 (b1 row);
// lane(g,m) holds k=4g..4g+3 of row m
DEVFN void loadIn6(const float* __restrict__ dims, const float* __restrict__ xyz,
                   int grp, int g, int m, int N, float (&buf)[2][4]) {
#pragma unroll
  for (int rt = 0; rt < 2; ++rt) { buf[rt][0] = buf[rt][1] = buf[rt][2] = buf[rt][3] = 0.f; }
  if (g == 0) {
#pragma unroll
    for (int rt = 0; rt < 2; ++rt) {
      int row = grp * 32 + rt * 16 + m;
      if (row < N) {
        const float* dp = dims + (size_t)row * 3u;
        buf[rt][0] = dp[0]; buf[rt][1] = dp[1]; buf[rt][2] = dp[2];
        buf[rt][3] = xyz[(size_t)row * 3u];
      }
    }
  } else if (g == 1) {
#pragma unroll
    for (int rt = 0; rt < 2; ++rt) {
      int row = grp * 32 + rt * 16 + m;
      if (row < N) {
        const float* xp = xyz + (size_t)row * 3u;
        buf[rt][0] = xp[1]; buf[rt][1] = xp[2];
      }
      buf[rt][2] = 1.f;   // k=6: constant-1 column -> b1 rides W1's k=6 row
    }
  }
}

__global__ void __launch_bounds__(BLOCK, 3)
pinn_mlp_kernel(const float* __restrict__ dims, const float* __restrict__ xyz,
                const float* __restrict__ W1, const float* __restrict__ b1,
                const float* __restrict__ W2, const float* __restrict__ b2,
                const float* __restrict__ W3, const float* __restrict__ b3,
                const float* __restrict__ W4, const float* __restrict__ b4,
                const float* __restrict__ W5, const float* __restrict__ b5,
                const float* __restrict__ W6, const float* __restrict__ b6,
                const float* __restrict__ W7, const float* __restrict__ b7,
                const float* __restrict__ W8, const float* __restrict__ b8,
                float* __restrict__ out, int N) {
  __shared__ __align__(16) unsigned char smem[SMEM_TOTAL];
  const int tid  = threadIdx.x;
  const int lane = tid & 63;
  const int wave = tid >> 6;
  const int m    = lane & 15;
  const int g    = lane >> 4;

  // ---------------- weight / bias packing (once per block, 8 waves share) ----------------
  for (int t = tid; t < 2048; t += BLOCK) {       // W1*log2e, k=6 row = b1*log2e
    int i = t & 3, ln = (t >> 2) & 63, nt = t >> 8;
    int k = 4 * (ln >> 4) + i;
    int n = 16 * nt + (ln & 15);
    float v = (k < 6) ? W1[k * 128 + n] * LOG2E : (k == 6 ? b1[n] * LOG2E : 0.f);
    *(__bf16*)(smem + OFF_W1 + (unsigned)nt * 512u + (unsigned)ln * 8u + (unsigned)i * 2u) = (__bf16)v;
  }
  packW(smem, OFF_W2, W2, 128, 48, tid);
  packW(smem, OFF_W3, W3, 48, 48, tid);
  packW(smem, OFF_W4, W4, 48, 48, tid);
  packW(smem, OFF_W5, W5, 48, 48, tid);
  packW(smem, OFF_W6, W6, 48, 48, tid);
  packW(smem, OFF_W7, W7, 48, 128, tid);
  float* sBw = (float*)(smem + OFF_BIAS);
  for (int t = tid; t < 512; t += BLOCK) {        // b2..b7 * log2e ; b8 raw ; pad 0
    float v;
    if      (t < 128) v = 0.f;
    else if (t < 176) v = b2[t - 128] * LOG2E;
    else if (t < 224) v = b3[t - 176] * LOG2E;
    else if (t < 272) v = b4[t - 224] * LOG2E;
    else if (t < 320) v = b5[t - 272] * LOG2E;
    else if (t < 368) v = b6[t - 320] * LOG2E;
    else if (t < 496) v = b7[t - 368] * LOG2E;
    else if (t < 499) v = b8[t - 496];
    else              v = 0.f;
    sBw[t] = v;
  }

  // W8 * ln2 in registers: A[n=m][k=16ks+4g+i], n<3 real (8 VGPRs)
  bf16x4 w8f[8];
#pragma unroll
  for (int ks = 0; ks < 8; ++ks) {
    w8f[ks][0] = (__bf16)0.f; w8f[ks][1] = (__bf16)0.f;
    w8f[ks][2] = (__bf16)0.f; w8f[ks][3] = (__bf16)0.f;
    if (m < 3) {
#pragma unroll
      for (int i = 0; i < 4; ++i) {
        int k = 16 * ks + 4 * g + i;
        w8f[ks][i] = (__bf16)(W8[k * 3 + m] * LN2);
      }
    }
  }

  __syncthreads();   // the ONLY workgroup barrier

  const float* sB = (const float*)(smem + OFF_BIAS);
  const unsigned wOff = (unsigned)lane * 8u;

  const int nGroups  = (N + 31) >> 5;
  const int gw0      = blockIdx.x * NWAVES + wave;
  const int gwStride = gridDim.x * NWAVES;

  float inC[2][4], inN[2][4];
  loadIn6(dims, xyz, gw0, g, m, N, inC);

  for (int grp = gw0; grp < nGroups; grp += gwStride) {
    const int base = grp * 32;

    // input B-frags (k=0..6 real incl. bias row, rest zero)
    bf16x4 x1[2];
#pragma unroll
    for (int rt = 0; rt < 2; ++rt)
#pragma unroll
      for (int j = 0; j < 4; ++j) x1[rt][j] = (__bf16)inC[rt][j];
    loadIn6(dims, xyz, grp + gwStride, g, m, N, inN);   // prefetch next group
    sbar();

    const f32x4 z4 = {0.f, 0.f, 0.f, 0.f};

    // ---- L1 -> L2 fused, 2 ntiles at a time (y = 8 regs transient) ----
    f32x4 acc2[2][3];
#pragma unroll
    for (int nt = 0; nt < 3; ++nt) {
      f32x4 bi = ldb(sB, 128, nt, g);                   // b2~
      acc2[0][nt] = bi; acc2[1][nt] = bi;
    }
#pragma unroll
    for (int p = 0; p < 4; ++p) {
      bf16x4 y[2][2];
#pragma unroll
      for (int c = 0; c < 2; ++c) {                     // produce L1 out ntile 2p+c
        int nt = 2 * p + c;
        bf16x4 w = ldw(smem, OFF_W1 + (unsigned)nt * 512u + wOff);
        y[0][c] = pksilu(mfma16(w, x1[0], z4));         // b1 rides W1 k=6
        y[1][c] = pksilu(mfma16(w, x1[1], z4));
      }
      sbar();
#pragma unroll
      for (int c = 0; c < 2; ++c) {                     // consume as L2 k-step 2p+c
        int ks = 2 * p + c;
#pragma unroll
        for (int nt = 0; nt < 3; ++nt) {
          bf16x4 w = ldw(smem, OFF_W2 + (unsigned)(ks * 3 + nt) * 512u + wOff);
          acc2[0][nt] = mfma16(w, y[0][c], acc2[0][nt]);
          acc2[1][nt] = mfma16(w, y[1][c], acc2[1][nt]);
        }
      }
      sbar();
    }
    bf16x4 xa[2][3], xb[2][3];
#pragma unroll
    for (int nt = 0; nt < 3; ++nt) {
      xa[0][nt] = pksilu(acc2[0][nt]);
      xa[1][nt] = pksilu(acc2[1][nt]);
    }
    sbar();

    // ---- 48-wide chain, all in registers ----
    layer33(smem, OFF_W3, sB, 176, wOff, g, xa, xb); sbar();
    layer33(smem, OFF_W4, sB, 224, wOff, g, xb, xa); sbar();
    layer33(smem, OFF_W5, sB, 272, wOff, g, xa, xb); sbar();
    layer33(smem, OFF_W6, sB, 320, wOff, g, xb, xa); sbar();
    // xa = x6~ (input to L7)

    // ---- L7 -> L8 fused, 2 ntiles at a time (a7 = 16 regs transient) ----
    f32x4 acc8[2];
    {
      f32x4 bi8 = ldb(sB, 496, 0, g);                   // b8 padded (zeros for g>0)
      acc8[0] = bi8; acc8[1] = bi8;
    }
#pragma unroll
    for (int p = 0; p < 4; ++p) {
      f32x4 a7[2][2];
#pragma unroll
      for (int c = 0; c < 2; ++c) {
        f32x4 bi = ldb(sB, 368, 2 * p + c, g);          // b7~
        a7[0][c] = bi; a7[1][c] = bi;
      }
#pragma unroll
      for (int ks = 0; ks < 3; ++ks)
#pragma unroll
        for (int c = 0; c < 2; ++c) {
          bf16x4 w = ldw(smem, OFF_W7 + (unsigned)(ks * 8 + 2 * p + c) * 512u + wOff);
          a7[0][c] = mfma16(w, xa[0][ks], a7[0][c]);
          a7[1][c] = mfma16(w, xa[1][ks], a7[1][c]);
        }
      sbar();
#pragma unroll
      for (int c = 0; c < 2; ++c) {
        bf16x4 x7a = pksilu(a7[0][c]);
        bf16x4 x7b = pksilu(a7[1][c]);
        acc8[0] = mfma16(w8f[2 * p + c], x7a, acc8[0]);
        acc8[1] = mfma16(w8f[2 * p + c], x7b, acc8[1]);
      }
      sbar();
    }

    // ---- store fp32 output: lane (g==0, m) owns row base+16rt+m, 3 consecutive floats ----
    if (g == 0) {
#pragma unroll
      for (int rt = 0; rt < 2; ++rt) {
        int row = base + rt * 16 + m;
        if (row < N) {
          size_t o = (size_t)row * 3u;
          out[o + 0] = acc8[rt][0];
          out[o + 1] = acc8[rt][1];
          out[o + 2] = acc8[rt][2];
        }
      }
    }

    // rotate prefetched inputs
#pragma unroll
    for (int rt = 0; rt < 2; ++rt)
#pragma unroll
      for (int j = 0; j < 4; ++j) inC[rt][j] = inN[rt][j];
  }
}

extern "C" void kernel_launch(void* const* d_in, const int* in_sizes, int n_in,
                              void* d_out, int out_size, void* d_ws, size_t ws_size,
                              hipStream_t stream) {
  const float* dims = (const float*)d_in[0];
  const float* xyz  = (const float*)d_in[1];
  const float* W1 = (const float*)d_in[2];  const float* b1 = (const float*)d_in[3];
  const float* W2 = (const float*)d_in[4];  const float* b2 = (const float*)d_in[5];
  const float* W3 = (const float*)d_in[6];  const float* b3 = (const float*)d_in[7];
  const float* W4 = (const float*)d_in[8];  const float* b4 = (const float*)d_in[9];
  const float* W5 = (const float*)d_in[10]; const float* b5 = (const float*)d_in[11];
  const float* W6 = (const float*)d_in[12]; const float* b6 = (const float*)d_in[13];
  const float* W7 = (const float*)d_in[14]; const float* b7 = (const float*)d_in[15];
  const float* W8 = (const float*)d_in[16]; const float* b8 = (const float*)d_in[17];
  float* out = (float*)d_out;
  const int N = in_sizes[0] / 3;

  pinn_mlp_kernel<<<dim3(512), dim3(BLOCK), 0, stream>>>(
      dims, xyz, W1, b1, W2, b2, W3, b3, W4, b4, W5, b5, W6, b6, W7, b7, W8, b8,
      out, N);
}